// Round 1
// baseline (9387.384 us; speedup 1.0000x reference)
//
#include <hip/hip_runtime.h>
#include <hip/hip_bf16.h>
#include <math.h>

// Problem constants
#define BB 64
#define HW 196
#define FEAT 2048
#define EMB 512
#define HID 1024
#define ATT 512
#define VOCAB 10000
#define TT 20
#define STEPS 19

__device__ __forceinline__ float sigmoidf_(float x) { return 1.0f / (1.0f + expf(-x)); }

// ---------------------------------------------------------------------------
// Generic NT GEMM: C[M][N] = A[M][K] . B[N][K]^T + bias[N]
// BM=64, BN=64, BK=16, 256 threads, 4x4 micro-tile. M must be multiple of 64.
// N may be ragged (guarded).
// ---------------------------------------------------------------------------
__global__ __launch_bounds__(256) void gemm_nt64(
    const float* __restrict__ A, const float* __restrict__ Bm,
    const float* __restrict__ bias, float* __restrict__ C,
    int M, int N, int K)
{
    __shared__ float As[16][65];
    __shared__ float Bs[16][65];
    const int tid = threadIdx.x;
    const int m0 = blockIdx.y * 64;
    const int n0 = blockIdx.x * 64;
    const int tm0 = (tid >> 4) << 2;
    const int tn0 = (tid & 15) << 2;
    const int lr = tid >> 2;           // 0..63
    const int lk = (tid & 3) << 2;     // 0,4,8,12

    float acc[4][4] = {};

    for (int k0 = 0; k0 < K; k0 += 16) {
        float4 av = *(const float4*)(A + (size_t)(m0 + lr) * K + k0 + lk);
        As[lk + 0][lr] = av.x; As[lk + 1][lr] = av.y;
        As[lk + 2][lr] = av.z; As[lk + 3][lr] = av.w;
        float4 bv = make_float4(0.f, 0.f, 0.f, 0.f);
        if (n0 + lr < N)
            bv = *(const float4*)(Bm + (size_t)(n0 + lr) * K + k0 + lk);
        Bs[lk + 0][lr] = bv.x; Bs[lk + 1][lr] = bv.y;
        Bs[lk + 2][lr] = bv.z; Bs[lk + 3][lr] = bv.w;
        __syncthreads();
        #pragma unroll
        for (int k = 0; k < 16; ++k) {
            float a0 = As[k][tm0 + 0], a1 = As[k][tm0 + 1];
            float a2 = As[k][tm0 + 2], a3 = As[k][tm0 + 3];
            float b0 = Bs[k][tn0 + 0], b1 = Bs[k][tn0 + 1];
            float b2 = Bs[k][tn0 + 2], b3 = Bs[k][tn0 + 3];
            acc[0][0] = fmaf(a0, b0, acc[0][0]); acc[0][1] = fmaf(a0, b1, acc[0][1]);
            acc[0][2] = fmaf(a0, b2, acc[0][2]); acc[0][3] = fmaf(a0, b3, acc[0][3]);
            acc[1][0] = fmaf(a1, b0, acc[1][0]); acc[1][1] = fmaf(a1, b1, acc[1][1]);
            acc[1][2] = fmaf(a1, b2, acc[1][2]); acc[1][3] = fmaf(a1, b3, acc[1][3]);
            acc[2][0] = fmaf(a2, b0, acc[2][0]); acc[2][1] = fmaf(a2, b1, acc[2][1]);
            acc[2][2] = fmaf(a2, b2, acc[2][2]); acc[2][3] = fmaf(a2, b3, acc[2][3]);
            acc[3][0] = fmaf(a3, b0, acc[3][0]); acc[3][1] = fmaf(a3, b1, acc[3][1]);
            acc[3][2] = fmaf(a3, b2, acc[3][2]); acc[3][3] = fmaf(a3, b3, acc[3][3]);
        }
        __syncthreads();
    }

    #pragma unroll
    for (int i = 0; i < 4; ++i) {
        #pragma unroll
        for (int j = 0; j < 4; ++j) {
            int n = n0 + tn0 + j;
            if (n < N)
                C[(size_t)(m0 + tm0 + i) * N + n] = acc[i][j] + bias[n];
        }
    }
}

// ---------------------------------------------------------------------------
// Gates GEMM: gates[64][4096] = [x|ctx|hx][64][2048] . [W_ih|W_hh]^T + b_ih + b_hh
// M=64 (grid.y==1), N=4096, K=2048 (0:512 x, 512:1024 ctx, 1024:2048 hx)
// ---------------------------------------------------------------------------
__global__ __launch_bounds__(256) void gemm_gates(
    const float* __restrict__ xs_t, const float* __restrict__ ctx,
    const float* __restrict__ hx,
    const float* __restrict__ W_ih, const float* __restrict__ W_hh,
    const float* __restrict__ b_ih, const float* __restrict__ b_hh,
    float* __restrict__ gates)
{
    __shared__ float As[16][65];
    __shared__ float Bs[16][65];
    const int tid = threadIdx.x;
    const int n0 = blockIdx.x * 64;
    const int tm0 = (tid >> 4) << 2;
    const int tn0 = (tid & 15) << 2;
    const int lr = tid >> 2;
    const int lk = (tid & 3) << 2;

    float acc[4][4] = {};

    for (int k0 = 0; k0 < 2048; k0 += 16) {
        const float* Asrc; int ld, kk;
        if (k0 < 512)       { Asrc = xs_t; ld = 512;  kk = k0; }
        else if (k0 < 1024) { Asrc = ctx;  ld = 512;  kk = k0 - 512; }
        else                { Asrc = hx;   ld = 1024; kk = k0 - 1024; }
        float4 av = *(const float4*)(Asrc + (size_t)lr * ld + kk + lk);
        As[lk + 0][lr] = av.x; As[lk + 1][lr] = av.y;
        As[lk + 2][lr] = av.z; As[lk + 3][lr] = av.w;

        const float* Bsrc; int kb;
        if (k0 < 1024) { Bsrc = W_ih; kb = k0; }
        else           { Bsrc = W_hh; kb = k0 - 1024; }
        float4 bv = *(const float4*)(Bsrc + (size_t)(n0 + lr) * 1024 + kb + lk);
        Bs[lk + 0][lr] = bv.x; Bs[lk + 1][lr] = bv.y;
        Bs[lk + 2][lr] = bv.z; Bs[lk + 3][lr] = bv.w;
        __syncthreads();
        #pragma unroll
        for (int k = 0; k < 16; ++k) {
            float a0 = As[k][tm0 + 0], a1 = As[k][tm0 + 1];
            float a2 = As[k][tm0 + 2], a3 = As[k][tm0 + 3];
            float b0 = Bs[k][tn0 + 0], b1 = Bs[k][tn0 + 1];
            float b2 = Bs[k][tn0 + 2], b3 = Bs[k][tn0 + 3];
            acc[0][0] = fmaf(a0, b0, acc[0][0]); acc[0][1] = fmaf(a0, b1, acc[0][1]);
            acc[0][2] = fmaf(a0, b2, acc[0][2]); acc[0][3] = fmaf(a0, b3, acc[0][3]);
            acc[1][0] = fmaf(a1, b0, acc[1][0]); acc[1][1] = fmaf(a1, b1, acc[1][1]);
            acc[1][2] = fmaf(a1, b2, acc[1][2]); acc[1][3] = fmaf(a1, b3, acc[1][3]);
            acc[2][0] = fmaf(a2, b0, acc[2][0]); acc[2][1] = fmaf(a2, b1, acc[2][1]);
            acc[2][2] = fmaf(a2, b2, acc[2][2]); acc[2][3] = fmaf(a2, b3, acc[2][3]);
            acc[3][0] = fmaf(a3, b0, acc[3][0]); acc[3][1] = fmaf(a3, b1, acc[3][1]);
            acc[3][2] = fmaf(a3, b2, acc[3][2]); acc[3][3] = fmaf(a3, b3, acc[3][3]);
        }
        __syncthreads();
    }

    #pragma unroll
    for (int i = 0; i < 4; ++i)
        #pragma unroll
        for (int j = 0; j < 4; ++j) {
            int n = n0 + tn0 + j;
            gates[(size_t)(tm0 + i) * 4096 + n] = acc[i][j] + b_ih[n] + b_hh[n];
        }
}

// ---------------------------------------------------------------------------
// fmean[b][e] = mean over h of f[b][h][e]
// ---------------------------------------------------------------------------
__global__ __launch_bounds__(256) void k_fmean(const float* __restrict__ f,
                                               float* __restrict__ fmean)
{
    int b = blockIdx.x, tid = threadIdx.x;
    for (int e = tid; e < EMB; e += 256) {
        const float* fb = f + (size_t)b * HW * EMB + e;
        float s = 0.f;
        for (int h = 0; h < HW; ++h) s += fb[(size_t)h * EMB];
        fmean[b * EMB + e] = s * (1.0f / HW);
    }
}

// ---------------------------------------------------------------------------
// hx0 = fmean @ W_hi^T + b_hi ; cx0 = fmean @ W_ci^T + b_ci
// ---------------------------------------------------------------------------
__global__ __launch_bounds__(256) void k_init(
    const float* __restrict__ fmean,
    const float* __restrict__ W_hi, const float* __restrict__ b_hi,
    const float* __restrict__ W_ci, const float* __restrict__ b_ci,
    float* __restrict__ hx, float* __restrict__ cx)
{
    int b = blockIdx.x, tid = threadIdx.x;
    __shared__ float fm[EMB];
    for (int i = tid; i < EMB; i += 256) fm[i] = fmean[b * EMB + i];
    __syncthreads();
    for (int u = tid; u < HID; u += 256) {
        const float4* w1 = (const float4*)(W_hi + (size_t)u * EMB);
        const float4* w2 = (const float4*)(W_ci + (size_t)u * EMB);
        float a1 = b_hi[u], a2 = b_ci[u];
        for (int k = 0; k < EMB / 4; ++k) {
            float4 y1 = w1[k], y2 = w2[k];
            float x0 = fm[4*k], x1 = fm[4*k+1], x2 = fm[4*k+2], x3 = fm[4*k+3];
            a1 += x0*y1.x + x1*y1.y + x2*y1.z + x3*y1.w;
            a2 += x0*y2.x + x1*y2.y + x2*y2.z + x3*y2.w;
        }
        hx[b * HID + u] = a1;
        cx[b * HID + u] = a2;
    }
}

// ---------------------------------------------------------------------------
// xs[t][b][:] = E[captions[b][t]][:]   for t < STEPS
// ---------------------------------------------------------------------------
__global__ __launch_bounds__(128) void k_embed(const int* __restrict__ cap,
                                               const float* __restrict__ E,
                                               float* __restrict__ xs)
{
    int blk = blockIdx.x;
    int t = blk / BB, b = blk % BB;
    int c = cap[b * TT + t];
    const float4* src = (const float4*)(E + (size_t)c * EMB);
    float4* dst = (float4*)(xs + ((size_t)t * BB + b) * EMB);
    dst[threadIdx.x] = src[threadIdx.x];
}

// ---------------------------------------------------------------------------
// Attention for one step: one block per batch element b.
//   ha = hx[b] @ W2^T + b2                       (ATT=512, K=HID=1024)
//   logits[h] = sum_a tanh(fa[b][h][a]+ha[a])*V[a] + bV
//   w = softmax_h(logits)
//   ctx[b][e] = sum_h w[h]*f[b][h][e]
// ---------------------------------------------------------------------------
__global__ __launch_bounds__(256) void k_attention(
    const float* __restrict__ fa, const float* __restrict__ f,
    const float* __restrict__ hx,
    const float* __restrict__ W2, const float* __restrict__ b2,
    const float* __restrict__ V, const float* __restrict__ bV,
    float* __restrict__ ctx)
{
    int b = blockIdx.x, tid = threadIdx.x;
    __shared__ float hx_s[HID];
    __shared__ float ha_s[ATT];
    __shared__ float red_s[256];
    __shared__ float w_s[256];

    for (int i = tid; i < HID; i += 256) hx_s[i] = hx[b * HID + i];
    __syncthreads();

    for (int a = tid; a < ATT; a += 256) {
        const float4* w2r = (const float4*)(W2 + (size_t)a * HID);
        float acc = b2[a];
        #pragma unroll 8
        for (int k = 0; k < HID / 4; ++k) {
            float4 w = w2r[k];
            acc += hx_s[4*k]*w.x + hx_s[4*k+1]*w.y + hx_s[4*k+2]*w.z + hx_s[4*k+3]*w.w;
        }
        ha_s[a] = acc;
    }
    __syncthreads();

    int wave = tid >> 6, lane = tid & 63;
    float bv0 = bV[0];
    for (int h = wave; h < HW; h += 4) {
        const float* far = fa + ((size_t)b * HW + h) * ATT;
        float p = 0.f;
        #pragma unroll
        for (int i = 0; i < ATT / 64; ++i) {
            int a = lane + 64 * i;
            p += tanhf(far[a] + ha_s[a]) * V[a];
        }
        #pragma unroll
        for (int off = 32; off > 0; off >>= 1) p += __shfl_down(p, off);
        if (lane == 0) w_s[h] = p + bv0;
    }
    __syncthreads();

    // softmax over 196 values
    float v = (tid < HW) ? w_s[tid] : -INFINITY;
    red_s[tid] = v; __syncthreads();
    for (int s = 128; s > 0; s >>= 1) {
        if (tid < s) red_s[tid] = fmaxf(red_s[tid], red_s[tid + s]);
        __syncthreads();
    }
    float mx = red_s[0]; __syncthreads();
    float e = (tid < HW) ? expf(v - mx) : 0.f;
    red_s[tid] = e; __syncthreads();
    for (int s = 128; s > 0; s >>= 1) {
        if (tid < s) red_s[tid] += red_s[tid + s];
        __syncthreads();
    }
    float inv = 1.0f / red_s[0];
    if (tid < HW) w_s[tid] = e * inv;
    __syncthreads();

    // ctx
    for (int e0 = tid; e0 < EMB; e0 += 256) {
        const float* fb = f + (size_t)b * HW * EMB + e0;
        float acc = 0.f;
        for (int h = 0; h < HW; ++h) acc = fmaf(w_s[h], fb[(size_t)h * EMB], acc);
        ctx[b * EMB + e0] = acc;
    }
}

// ---------------------------------------------------------------------------
// LSTM pointwise: gate order i,f,g,o; in-place update of hx, cx.
// ---------------------------------------------------------------------------
__global__ __launch_bounds__(256) void k_lstm(const float* __restrict__ gates,
                                              float* __restrict__ hx,
                                              float* __restrict__ cx)
{
    int idx = blockIdx.x * 256 + threadIdx.x;   // 0..65535
    int b = idx >> 10, u = idx & 1023;
    const float* g = gates + (size_t)b * 4096;
    float ig = sigmoidf_(g[u]);
    float fg = sigmoidf_(g[1024 + u]);
    float gg = tanhf(g[2048 + u]);
    float og = sigmoidf_(g[3072 + u]);
    float c = fg * cx[idx] + ig * gg;
    float h = og * tanhf(c);
    cx[idx] = c;
    hx[idx] = h;
}

// ---------------------------------------------------------------------------
extern "C" void kernel_launch(void* const* d_in, const int* in_sizes, int n_in,
                              void* d_out, int out_size, void* d_ws, size_t ws_size,
                              hipStream_t stream) {
    const float* features = (const float*)d_in[0];
    const int*   captions = (const int*)d_in[1];
    // d_in[2] lengths: unused (uniform T)
    const float* E      = (const float*)d_in[3];
    const float* W_feat = (const float*)d_in[4];
    const float* b_feat = (const float*)d_in[5];
    const float* W1     = (const float*)d_in[6];
    const float* b1     = (const float*)d_in[7];
    const float* W2     = (const float*)d_in[8];
    const float* b2     = (const float*)d_in[9];
    const float* V      = (const float*)d_in[10];
    const float* bV     = (const float*)d_in[11];
    const float* W_hi   = (const float*)d_in[12];
    const float* b_hi   = (const float*)d_in[13];
    const float* W_ci   = (const float*)d_in[14];
    const float* b_ci   = (const float*)d_in[15];
    const float* W_ih   = (const float*)d_in[16];
    const float* b_ih   = (const float*)d_in[17];
    const float* W_hh   = (const float*)d_in[18];
    const float* b_hh   = (const float*)d_in[19];
    const float* W_out  = (const float*)d_in[20];
    const float* b_out  = (const float*)d_in[21];
    float* out = (float*)d_out;

    // workspace layout (floats)
    float* ws = (float*)d_ws;
    float* f_buf  = ws;                       // 12544*512  = 6,422,528
    float* fa_buf = f_buf + 6422528;          // 6,422,528
    float* xs     = fa_buf + 6422528;         // 19*64*512  = 622,592
    float* fmean  = xs + 622592;              // 64*512     = 32,768
    float* hx     = fmean + 32768;            // 64*1024    = 65,536
    float* cx     = hx + 65536;               // 65,536
    float* ctx    = cx + 65536;               // 64*512     = 32,768
    float* gates  = ctx + 32768;              // 64*4096    = 262,144

    // ---- precompute ----
    // f = features @ W_feat^T + b_feat   [12544, 512], K=2048
    gemm_nt64<<<dim3(EMB / 64, (BB * HW) / 64), 256, 0, stream>>>(
        features, W_feat, b_feat, f_buf, BB * HW, EMB, FEAT);
    // fa = f @ W1^T + b1                 [12544, 512], K=512
    gemm_nt64<<<dim3(ATT / 64, (BB * HW) / 64), 256, 0, stream>>>(
        f_buf, W1, b1, fa_buf, BB * HW, ATT, EMB);
    k_fmean<<<BB, 256, 0, stream>>>(f_buf, fmean);
    k_init<<<BB, 256, 0, stream>>>(fmean, W_hi, b_hi, W_ci, b_ci, hx, cx);
    k_embed<<<STEPS * BB, 128, 0, stream>>>(captions, E, xs);

    // ---- recurrent steps ----
    for (int t = 0; t < STEPS; ++t) {
        k_attention<<<BB, 256, 0, stream>>>(fa_buf, f_buf, hx, W2, b2, V, bV, ctx);
        gemm_gates<<<4096 / 64, 256, 0, stream>>>(
            xs + (size_t)t * BB * EMB, ctx, hx, W_ih, W_hh, b_ih, b_hh, gates);
        k_lstm<<<(BB * HID) / 256, 256, 0, stream>>>(gates, hx, cx);
        gemm_nt64<<<dim3((VOCAB + 63) / 64, 1), 256, 0, stream>>>(
            hx, W_out, b_out, out + (size_t)t * BB * VOCAB, BB, VOCAB, HID);
    }
}

// Round 2
// 5926.240 us; speedup vs baseline: 1.5840x; 1.5840x over previous
//
#include <hip/hip_runtime.h>
#include <hip/hip_bf16.h>
#include <math.h>

// Problem constants
#define BB 64
#define HW 196
#define FEAT 2048
#define EMB 512
#define HID 1024
#define ATT 512
#define VOCAB 10000
#define TT 20
#define STEPS 19

__device__ __forceinline__ float sigmoidf_(float x) { return 1.0f / (1.0f + expf(-x)); }

// ---------------------------------------------------------------------------
// Generic NT GEMM: C[M][N] = A[M][K] . B[N][K]^T + bias[N]
// BM=64, BN=64, BK=16, 256 threads, 4x4 micro-tile. Used for f and fa
// precompute. LDS padded to 68 (17 float4) so fragment reads are b128.
// ---------------------------------------------------------------------------
__global__ __launch_bounds__(256) void gemm_nt64(
    const float* __restrict__ A, const float* __restrict__ Bm,
    const float* __restrict__ bias, float* __restrict__ C,
    int M, int N, int K)
{
    __shared__ __align__(16) float As[16][68];
    __shared__ __align__(16) float Bs[16][68];
    const int tid = threadIdx.x;
    const int m0 = blockIdx.y * 64;
    const int n0 = blockIdx.x * 64;
    const int tm0 = (tid >> 4) << 2;
    const int tn0 = (tid & 15) << 2;
    const int lr = tid >> 2;           // 0..63
    const int lk = (tid & 3) << 2;     // 0,4,8,12

    float acc[4][4] = {};

    for (int k0 = 0; k0 < K; k0 += 16) {
        float4 av = *(const float4*)(A + (size_t)(m0 + lr) * K + k0 + lk);
        As[lk + 0][lr] = av.x; As[lk + 1][lr] = av.y;
        As[lk + 2][lr] = av.z; As[lk + 3][lr] = av.w;
        float4 bv = make_float4(0.f, 0.f, 0.f, 0.f);
        if (n0 + lr < N)
            bv = *(const float4*)(Bm + (size_t)(n0 + lr) * K + k0 + lk);
        Bs[lk + 0][lr] = bv.x; Bs[lk + 1][lr] = bv.y;
        Bs[lk + 2][lr] = bv.z; Bs[lk + 3][lr] = bv.w;
        __syncthreads();
        #pragma unroll
        for (int k = 0; k < 16; ++k) {
            float4 a = *(const float4*)&As[k][tm0];
            float4 b = *(const float4*)&Bs[k][tn0];
            acc[0][0] = fmaf(a.x, b.x, acc[0][0]); acc[0][1] = fmaf(a.x, b.y, acc[0][1]);
            acc[0][2] = fmaf(a.x, b.z, acc[0][2]); acc[0][3] = fmaf(a.x, b.w, acc[0][3]);
            acc[1][0] = fmaf(a.y, b.x, acc[1][0]); acc[1][1] = fmaf(a.y, b.y, acc[1][1]);
            acc[1][2] = fmaf(a.y, b.z, acc[1][2]); acc[1][3] = fmaf(a.y, b.w, acc[1][3]);
            acc[2][0] = fmaf(a.z, b.x, acc[2][0]); acc[2][1] = fmaf(a.z, b.y, acc[2][1]);
            acc[2][2] = fmaf(a.z, b.z, acc[2][2]); acc[2][3] = fmaf(a.z, b.w, acc[2][3]);
            acc[3][0] = fmaf(a.w, b.x, acc[3][0]); acc[3][1] = fmaf(a.w, b.y, acc[3][1]);
            acc[3][2] = fmaf(a.w, b.z, acc[3][2]); acc[3][3] = fmaf(a.w, b.w, acc[3][3]);
        }
        __syncthreads();
    }

    #pragma unroll
    for (int i = 0; i < 4; ++i) {
        #pragma unroll
        for (int j = 0; j < 4; ++j) {
            int n = n0 + tn0 + j;
            if (n < N)
                C[(size_t)(m0 + tm0 + i) * N + n] = acc[i][j] + bias[n];
        }
    }
}

// ---------------------------------------------------------------------------
// Skinny NT GEMM: C[64][N] = A[64][K] . W[N][K]^T + bias0 (+bias1)
// lane == batch row m (M=64 == wave width). A staged per 256-k chunk into
// LDS as XOR-swizzled float4 (conflict-free ds_read_b128). Each wave owns
// RPW consecutive output columns; W rows are wave-uniform float4 streams.
// A may be split into up to 3 row-major segments (k-lengths multiple of 256),
// each with its own weight matrix slice (ptr, ld, col offset).
// ---------------------------------------------------------------------------
template<int RPW>
__global__ __launch_bounds__(256) void skinny_nt(
    const float* __restrict__ A0, int len0,
    const float* __restrict__ A1, int len1,
    const float* __restrict__ A2, int len2,
    const float* __restrict__ Wm0, int wld0, int wcol0,
    const float* __restrict__ Wm1, int wld1, int wcol1,
    const float* __restrict__ Wm2, int wld2, int wcol2,
    const float* __restrict__ bias0, const float* __restrict__ bias1,
    float* __restrict__ C, int N, int ldc)
{
    __shared__ __align__(16) float lds_a[64 * 256];   // 64 KiB
    float4* lds4 = (float4*)lds_a;
    const int tid = threadIdx.x;
    const int lane = tid & 63;
    const int wid = __builtin_amdgcn_readfirstlane(tid >> 6);
    const int nbase = (blockIdx.x * 4 + wid) * RPW;

    const int sm = tid >> 2;       // staging row 0..63
    const int jb = tid & 3;        // staging float4 phase

    float acc[RPW];
    #pragma unroll
    for (int r = 0; r < RPW; ++r) acc[r] = 0.f;

    const int K = len0 + len1 + len2;
    for (int c0 = 0; c0 < K; c0 += 256) {
        const float* Aseg; int ald, kloc;
        const float* Wseg; int wld, wcol;
        if (c0 < len0) {
            Aseg = A0; ald = len0; kloc = c0;
            Wseg = Wm0; wld = wld0; wcol = wcol0 + c0;
        } else if (c0 < len0 + len1) {
            Aseg = A1; ald = len1; kloc = c0 - len0;
            Wseg = Wm1; wld = wld1; wcol = wcol1 + (c0 - len0);
        } else {
            Aseg = A2; ald = len2; kloc = c0 - len0 - len1;
            Wseg = Wm2; wld = wld2; wcol = wcol2 + (c0 - len0 - len1);
        }
        __syncthreads();   // previous chunk's reads done
        {
            const float* arow = Aseg + (size_t)sm * ald + kloc;
            #pragma unroll
            for (int i = 0; i < 16; ++i) {
                int j = (i << 2) | jb;                       // 0..63
                float4 v = *(const float4*)(arow + (j << 2));
                lds4[(sm << 6) | (j ^ (sm & 15))] = v;
            }
        }
        __syncthreads();

        const float* wr[RPW];
        #pragma unroll
        for (int r = 0; r < RPW; ++r)
            wr[r] = Wseg + (size_t)(nbase + r) * wld + wcol;

        #pragma unroll 4
        for (int j = 0; j < 64; ++j) {
            float4 a = lds4[(lane << 6) | (j ^ (lane & 15))];
            #pragma unroll
            for (int r = 0; r < RPW; ++r) {
                float4 w = *(const float4*)(wr[r] + (j << 2));
                acc[r] = fmaf(a.x, w.x, acc[r]);
                acc[r] = fmaf(a.y, w.y, acc[r]);
                acc[r] = fmaf(a.z, w.z, acc[r]);
                acc[r] = fmaf(a.w, w.w, acc[r]);
            }
        }
    }

    #pragma unroll
    for (int r = 0; r < RPW; ++r) {
        int n = nbase + r;
        float bsum = bias0[n];
        if (bias1) bsum += bias1[n];
        C[(size_t)lane * ldc + n] = acc[r] + bsum;
    }
}

// ---------------------------------------------------------------------------
// fmean[b][e] = mean over h of f[b][h][e]
// ---------------------------------------------------------------------------
__global__ __launch_bounds__(256) void k_fmean(const float* __restrict__ f,
                                               float* __restrict__ fmean)
{
    int b = blockIdx.x, tid = threadIdx.x;
    for (int e = tid; e < EMB; e += 256) {
        const float* fb = f + (size_t)b * HW * EMB + e;
        float s = 0.f;
        for (int h = 0; h < HW; ++h) s += fb[(size_t)h * EMB];
        fmean[b * EMB + e] = s * (1.0f / HW);
    }
}

// ---------------------------------------------------------------------------
// hx0 = fmean @ W_hi^T + b_hi ; cx0 = fmean @ W_ci^T + b_ci
// ---------------------------------------------------------------------------
__global__ __launch_bounds__(256) void k_init(
    const float* __restrict__ fmean,
    const float* __restrict__ W_hi, const float* __restrict__ b_hi,
    const float* __restrict__ W_ci, const float* __restrict__ b_ci,
    float* __restrict__ hx, float* __restrict__ cx)
{
    int b = blockIdx.x, tid = threadIdx.x;
    __shared__ float fm[EMB];
    for (int i = tid; i < EMB; i += 256) fm[i] = fmean[b * EMB + i];
    __syncthreads();
    for (int u = tid; u < HID; u += 256) {
        const float4* w1 = (const float4*)(W_hi + (size_t)u * EMB);
        const float4* w2 = (const float4*)(W_ci + (size_t)u * EMB);
        float a1 = b_hi[u], a2 = b_ci[u];
        for (int k = 0; k < EMB / 4; ++k) {
            float4 y1 = w1[k], y2 = w2[k];
            float x0 = fm[4*k], x1 = fm[4*k+1], x2 = fm[4*k+2], x3 = fm[4*k+3];
            a1 += x0*y1.x + x1*y1.y + x2*y1.z + x3*y1.w;
            a2 += x0*y2.x + x1*y2.y + x2*y2.z + x3*y2.w;
        }
        hx[b * HID + u] = a1;
        cx[b * HID + u] = a2;
    }
}

// ---------------------------------------------------------------------------
// xs[t][b][:] = E[captions[b][t]][:]   for t < STEPS
// ---------------------------------------------------------------------------
__global__ __launch_bounds__(128) void k_embed(const int* __restrict__ cap,
                                               const float* __restrict__ E,
                                               float* __restrict__ xs)
{
    int blk = blockIdx.x;
    int t = blk / BB, b = blk % BB;
    int c = cap[b * TT + t];
    const float4* src = (const float4*)(E + (size_t)c * EMB);
    float4* dst = (float4*)(xs + ((size_t)t * BB + b) * EMB);
    dst[threadIdx.x] = src[threadIdx.x];
}

// ---------------------------------------------------------------------------
// Attention logits. grid = 64*4 blocks: b = blk>>2, hg = blk&3 (49 h's each).
// Each block recomputes ha = hx[b] @ W2^T + b2 (cheap, L2-resident W2), then
// logits[b][h] = sum_a tanh(fa[b][h][a]+ha[a])*V[a] + bV for its h-slice.
// ---------------------------------------------------------------------------
__global__ __launch_bounds__(256) void k_logits(
    const float* __restrict__ fa, const float* __restrict__ hx,
    const float* __restrict__ W2, const float* __restrict__ b2,
    const float* __restrict__ V, const float* __restrict__ bV,
    float* __restrict__ logits)
{
    int blk = blockIdx.x;
    int b = blk >> 2, hg = blk & 3;
    int tid = threadIdx.x;
    __shared__ __align__(16) float hx_s[HID];
    __shared__ float ha_s[ATT];
    __shared__ float V_s[ATT];

    for (int i = tid; i < HID; i += 256) hx_s[i] = hx[b * HID + i];
    for (int a = tid; a < ATT; a += 256) V_s[a] = V[a];
    __syncthreads();

    for (int a = tid; a < ATT; a += 256) {
        const float4* w2r = (const float4*)(W2 + (size_t)a * HID);
        float acc = b2[a];
        #pragma unroll 8
        for (int k = 0; k < HID / 4; ++k) {
            float4 w = w2r[k];
            float4 x = *(const float4*)&hx_s[4 * k];
            acc += x.x*w.x + x.y*w.y + x.z*w.z + x.w*w.w;
        }
        ha_s[a] = acc;
    }
    __syncthreads();

    int wid = tid >> 6, lane = tid & 63;
    float bv0 = bV[0];
    for (int h = hg * 49 + wid; h < hg * 49 + 49; h += 4) {
        const float* far = fa + ((size_t)b * HW + h) * ATT;
        float p = 0.f;
        #pragma unroll
        for (int i = 0; i < ATT / 64; ++i) {
            int a = lane + (i << 6);
            p += tanhf(far[a] + ha_s[a]) * V_s[a];
        }
        #pragma unroll
        for (int off = 32; off > 0; off >>= 1) p += __shfl_down(p, off);
        if (lane == 0) logits[b * HW + h] = p + bv0;
    }
}

// ---------------------------------------------------------------------------
// ctx. grid = 64*4 blocks: b = blk>>2, eg = blk&3 (128 e's each). Each block
// recomputes softmax over the 196 logits (trivial), then
// ctx[b][e] = sum_h w[h]*f[b][h][e] with the h-range split over two halves.
// ---------------------------------------------------------------------------
__global__ __launch_bounds__(256) void k_ctx(
    const float* __restrict__ logits, const float* __restrict__ f,
    float* __restrict__ ctx)
{
    int blk = blockIdx.x;
    int b = blk >> 2, eg = blk & 3;
    int tid = threadIdx.x;
    __shared__ float w_s[HW];
    __shared__ float red_s[256];
    __shared__ float part[128];

    float v = (tid < HW) ? logits[b * HW + tid] : -INFINITY;
    red_s[tid] = v; __syncthreads();
    for (int s = 128; s > 0; s >>= 1) {
        if (tid < s) red_s[tid] = fmaxf(red_s[tid], red_s[tid + s]);
        __syncthreads();
    }
    float mx = red_s[0]; __syncthreads();
    float e = (tid < HW) ? expf(v - mx) : 0.f;
    red_s[tid] = e; __syncthreads();
    for (int s = 128; s > 0; s >>= 1) {
        if (tid < s) red_s[tid] += red_s[tid + s];
        __syncthreads();
    }
    float inv = 1.0f / red_s[0];
    if (tid < HW) w_s[tid] = e * inv;
    __syncthreads();

    int e0 = (eg << 7) + (tid & 127);
    int half = tid >> 7;
    const float* fb = f + (size_t)b * HW * EMB + e0;
    float s = 0.f;
    int h0 = half * 98;
    for (int h = h0; h < h0 + 98; ++h)
        s = fmaf(w_s[h], fb[(size_t)h * EMB], s);
    if (half) part[tid & 127] = s;
    __syncthreads();
    if (!half) ctx[b * EMB + e0] = s + part[tid];
}

// ---------------------------------------------------------------------------
// LSTM pointwise: gate order i,f,g,o; in-place update of hx, cx.
// ---------------------------------------------------------------------------
__global__ __launch_bounds__(256) void k_lstm(const float* __restrict__ gates,
                                              float* __restrict__ hx,
                                              float* __restrict__ cx)
{
    int idx = blockIdx.x * 256 + threadIdx.x;   // 0..65535
    int b = idx >> 10, u = idx & 1023;
    const float* g = gates + (size_t)b * 4096;
    float ig = sigmoidf_(g[u]);
    float fg = sigmoidf_(g[1024 + u]);
    float gg = tanhf(g[2048 + u]);
    float og = sigmoidf_(g[3072 + u]);
    float c = fg * cx[idx] + ig * gg;
    float h = og * tanhf(c);
    cx[idx] = c;
    hx[idx] = h;
}

// ---------------------------------------------------------------------------
extern "C" void kernel_launch(void* const* d_in, const int* in_sizes, int n_in,
                              void* d_out, int out_size, void* d_ws, size_t ws_size,
                              hipStream_t stream) {
    const float* features = (const float*)d_in[0];
    const int*   captions = (const int*)d_in[1];
    // d_in[2] lengths: unused (uniform T)
    const float* E      = (const float*)d_in[3];
    const float* W_feat = (const float*)d_in[4];
    const float* b_feat = (const float*)d_in[5];
    const float* W1     = (const float*)d_in[6];
    const float* b1     = (const float*)d_in[7];
    const float* W2     = (const float*)d_in[8];
    const float* b2     = (const float*)d_in[9];
    const float* V      = (const float*)d_in[10];
    const float* bV     = (const float*)d_in[11];
    const float* W_hi   = (const float*)d_in[12];
    const float* b_hi   = (const float*)d_in[13];
    const float* W_ci   = (const float*)d_in[14];
    const float* b_ci   = (const float*)d_in[15];
    const float* W_ih   = (const float*)d_in[16];
    const float* b_ih   = (const float*)d_in[17];
    const float* W_hh   = (const float*)d_in[18];
    const float* b_hh   = (const float*)d_in[19];
    const float* W_out  = (const float*)d_in[20];
    const float* b_out  = (const float*)d_in[21];
    float* out = (float*)d_out;

    // workspace layout (floats)
    float* ws = (float*)d_ws;
    float* f_buf  = ws;                       // 12544*512  = 6,422,528
    float* fa_buf = f_buf + 6422528;          // 6,422,528
    float* xs     = fa_buf + 6422528;         // 19*64*512  = 622,592
    float* fmean  = xs + 622592;              // 64*512     = 32,768
    float* hx     = fmean + 32768;            // 64*1024    = 65,536
    float* cx     = hx + 65536;               // 65,536
    float* ctx    = cx + 65536;               // 64*512     = 32,768
    float* gates  = ctx + 32768;              // 64*4096    = 262,144
    float* logits = gates + 262144;           // 64*196     = 12,544

    // ---- precompute ----
    gemm_nt64<<<dim3(EMB / 64, (BB * HW) / 64), 256, 0, stream>>>(
        features, W_feat, b_feat, f_buf, BB * HW, EMB, FEAT);
    gemm_nt64<<<dim3(ATT / 64, (BB * HW) / 64), 256, 0, stream>>>(
        f_buf, W1, b1, fa_buf, BB * HW, ATT, EMB);
    k_fmean<<<BB, 256, 0, stream>>>(f_buf, fmean);
    k_init<<<BB, 256, 0, stream>>>(fmean, W_hi, b_hi, W_ci, b_ci, hx, cx);
    k_embed<<<STEPS * BB, 128, 0, stream>>>(captions, E, xs);

    // ---- recurrent steps ----
    for (int t = 0; t < STEPS; ++t) {
        k_logits<<<BB * 4, 256, 0, stream>>>(fa_buf, hx, W2, b2, V, bV, logits);
        k_ctx<<<BB * 4, 256, 0, stream>>>(logits, f_buf, ctx);
        // gates = [x|ctx|hx] . [W_ih|W_hh]^T + b_ih + b_hh   (N=4096, K=2048)
        skinny_nt<2><<<512, 256, 0, stream>>>(
            xs + (size_t)t * BB * EMB, 512, ctx, 512, hx, 1024,
            W_ih, 1024, 0, W_ih, 1024, 512, W_hh, 1024, 0,
            b_ih, b_hh, gates, 4096, 4096);
        k_lstm<<<(BB * HID) / 256, 256, 0, stream>>>(gates, hx, cx);
        // out = hx . W_out^T + b_out   (N=10000, K=1024)
        skinny_nt<4><<<625, 256, 0, stream>>>(
            hx, 1024, hx, 0, hx, 0,
            W_out, 1024, 0, W_out, 1024, 0, W_out, 1024, 0,
            b_out, nullptr, out + (size_t)t * BB * VOCAB, VOCAB, VOCAB);
    }
}

// Round 3
// 3784.463 us; speedup vs baseline: 2.4805x; 1.5659x over previous
//
#include <hip/hip_runtime.h>
#include <hip/hip_bf16.h>
#include <math.h>

#define BB 64
#define HW 196
#define FEAT 2048
#define EMB 512
#define HID 1024
#define ATT 512
#define VOCAB 10000
#define TT 20
#define STEPS 19

__device__ __forceinline__ float sigmoidf_(float x) { return 1.0f / (1.0f + expf(-x)); }

using bfrag = __attribute__((ext_vector_type(8))) short;   // 8 bf16 = 4 VGPR
using f32x4 = __attribute__((ext_vector_type(4))) float;

__device__ __forceinline__ ushort f2bf_rne(float f) {
    unsigned u = __float_as_uint(f);
    unsigned r = (u + 0x7FFFu + ((u >> 16) & 1u)) >> 16;
    return (ushort)r;
}
__device__ __forceinline__ float bf2f(ushort h) {
    return __uint_as_float(((unsigned)h) << 16);
}

// ---------------------------------------------------------------------------
// fp32 -> split bf16 planes: x = hi + lo (+ ~2^-18 rel).  n % 1024 == 0.
// ---------------------------------------------------------------------------
__global__ __launch_bounds__(256) void k_split(const float* __restrict__ x,
                                               ushort* __restrict__ hi,
                                               ushort* __restrict__ lo, int n)
{
    int i4 = (blockIdx.x * 256 + threadIdx.x) * 4;
    if (i4 >= n) return;
    float4 v = *(const float4*)(x + i4);
    float av[4] = {v.x, v.y, v.z, v.w};
    #pragma unroll
    for (int j = 0; j < 4; ++j) {
        ushort h = f2bf_rne(av[j]);
        hi[i4 + j] = h;
        lo[i4 + j] = f2bf_rne(av[j] - bf2f(h));
    }
}

// ---------------------------------------------------------------------------
// MFMA split-bf16 NT GEMM: C[M][N] = A[M][K] . B[N][K]^T + bias[N]
// A fp32 (converted to hi/lo during staging); B pre-split bf16 planes.
// 3-term: Ah*Bh + Ah*Bl + Al*Bh.  Tile 64(M) x 256(N), BK=32, 4 waves,
// each wave a 64x64 sub-tile via 4x4 grid of 16x16x32 MFMA.
// grid = (ceil(N/256), Marows/64).  Store guarded by Mvalid/N.
// C/D layout (m89-verified): col = lane&15, row = (lane>>4)*4 + reg.
// ---------------------------------------------------------------------------
__global__ __launch_bounds__(256) void mfma_nt(
    const float* __restrict__ A,
    const ushort* __restrict__ Bhi, const ushort* __restrict__ Blo,
    const float* __restrict__ bias, float* __restrict__ C,
    int Mvalid, int N, int K, int ldc)
{
    __shared__ __align__(16) ushort sAh[4][64][8];
    __shared__ __align__(16) ushort sAl[4][64][8];
    __shared__ __align__(16) ushort sBh[4][256][8];
    __shared__ __align__(16) ushort sBl[4][256][8];

    const int tid = threadIdx.x;
    const int m0 = blockIdx.y * 64;
    const int n0 = blockIdx.x * 256;

    const int ag = tid >> 6, ar = tid & 63;            // A staging cell
    const float* aptr = A + (size_t)(m0 + ar) * K + ag * 8;
    const int nr = min(n0 + tid, N - 1);               // B staging row (clamped)
    const ushort* bhp = Bhi + (size_t)nr * K;
    const ushort* blp = Blo + (size_t)nr * K;

    const int lane = tid & 63;
    const int w = tid >> 6;
    const int g = lane >> 4, l15 = lane & 15;

    f32x4 acc[4][4] = {};

    for (int k0 = 0; k0 < K; k0 += 32) {
        __syncthreads();
        {   // A: fp32 -> split bf16 into LDS
            float av[8];
            *(float4*)(av)     = *(const float4*)(aptr + k0);
            *(float4*)(av + 4) = *(const float4*)(aptr + k0 + 4);
            bfrag vh, vl;
            #pragma unroll
            for (int j = 0; j < 8; ++j) {
                ushort h = f2bf_rne(av[j]);
                vh[j] = (short)h;
                vl[j] = (short)f2bf_rne(av[j] - bf2f(h));
            }
            *(bfrag*)&sAh[ag][ar][0] = vh;
            *(bfrag*)&sAl[ag][ar][0] = vl;
        }
        #pragma unroll
        for (int q = 0; q < 4; ++q) {  // B planes: 64B/row contiguous
            *(bfrag*)&sBh[q][tid][0] = *(const bfrag*)(bhp + k0 + q * 8);
            *(bfrag*)&sBl[q][tid][0] = *(const bfrag*)(blp + k0 + q * 8);
        }
        __syncthreads();

        bfrag ah[4], al[4], bh[4], bl[4];
        #pragma unroll
        for (int s = 0; s < 4; ++s) {
            ah[s] = *(const bfrag*)&sAh[g][s * 16 + l15][0];
            al[s] = *(const bfrag*)&sAl[g][s * 16 + l15][0];
        }
        #pragma unroll
        for (int u = 0; u < 4; ++u) {
            bh[u] = *(const bfrag*)&sBh[g][w * 64 + u * 16 + l15][0];
            bl[u] = *(const bfrag*)&sBl[g][w * 64 + u * 16 + l15][0];
        }
        #pragma unroll
        for (int s = 0; s < 4; ++s)
            #pragma unroll
            for (int u = 0; u < 4; ++u) {
                acc[s][u] = __builtin_amdgcn_mfma_f32_16x16x32_bf16(ah[s], bh[u], acc[s][u], 0, 0, 0);
                acc[s][u] = __builtin_amdgcn_mfma_f32_16x16x32_bf16(ah[s], bl[u], acc[s][u], 0, 0, 0);
                acc[s][u] = __builtin_amdgcn_mfma_f32_16x16x32_bf16(al[s], bh[u], acc[s][u], 0, 0, 0);
            }
    }

    #pragma unroll
    for (int s = 0; s < 4; ++s)
        #pragma unroll
        for (int u = 0; u < 4; ++u) {
            int col = n0 + w * 64 + u * 16 + l15;
            if (col < N) {
                float bv = bias[col];
                #pragma unroll
                for (int r = 0; r < 4; ++r) {
                    int row = m0 + s * 16 + g * 4 + r;
                    if (row < Mvalid)
                        C[(size_t)row * ldc + col] = acc[s][u][r] + bv;
                }
            }
        }
}

// ---------------------------------------------------------------------------
// Gates split-K GEMM: pg[ks][64][4096] partials, ks selects one 512-k segment
// of [x|ctx|hx(0:512)|hx(512:1024)] and matching W_ih/W_hh column slice.
// grid = (64, 4).  BM=64(all M) x BN=64, BK=16, 4x4 micro-tile fp32.
// ---------------------------------------------------------------------------
__global__ __launch_bounds__(256) void gemm_gates_ks(
    const float* __restrict__ xs_t, const float* __restrict__ ctx,
    const float* __restrict__ hx,
    const float* __restrict__ W_ih, const float* __restrict__ W_hh,
    float* __restrict__ pg)
{
    __shared__ __align__(16) float As[16][68];
    __shared__ __align__(16) float Bs[16][68];
    const int tid = threadIdx.x;
    const int ks = blockIdx.y;
    const int n0 = blockIdx.x * 64;
    const float* A; int ald, aoff; const float* Wm; int wcol;
    if (ks == 0)      { A = xs_t; ald = 512;  aoff = 0;   Wm = W_ih; wcol = 0; }
    else if (ks == 1) { A = ctx;  ald = 512;  aoff = 0;   Wm = W_ih; wcol = 512; }
    else if (ks == 2) { A = hx;   ald = 1024; aoff = 0;   Wm = W_hh; wcol = 0; }
    else              { A = hx;   ald = 1024; aoff = 512; Wm = W_hh; wcol = 512; }

    const int tm0 = (tid >> 4) << 2;
    const int tn0 = (tid & 15) << 2;
    const int lr = tid >> 2;
    const int lk = (tid & 3) << 2;
    float acc[4][4] = {};

    for (int k0 = 0; k0 < 512; k0 += 16) {
        float4 av = *(const float4*)(A + (size_t)lr * ald + aoff + k0 + lk);
        As[lk + 0][lr] = av.x; As[lk + 1][lr] = av.y;
        As[lk + 2][lr] = av.z; As[lk + 3][lr] = av.w;
        float4 bv = *(const float4*)(Wm + (size_t)(n0 + lr) * 1024 + wcol + k0 + lk);
        Bs[lk + 0][lr] = bv.x; Bs[lk + 1][lr] = bv.y;
        Bs[lk + 2][lr] = bv.z; Bs[lk + 3][lr] = bv.w;
        __syncthreads();
        #pragma unroll
        for (int k = 0; k < 16; ++k) {
            float4 a = *(const float4*)&As[k][tm0];
            float4 b = *(const float4*)&Bs[k][tn0];
            acc[0][0] = fmaf(a.x, b.x, acc[0][0]); acc[0][1] = fmaf(a.x, b.y, acc[0][1]);
            acc[0][2] = fmaf(a.x, b.z, acc[0][2]); acc[0][3] = fmaf(a.x, b.w, acc[0][3]);
            acc[1][0] = fmaf(a.y, b.x, acc[1][0]); acc[1][1] = fmaf(a.y, b.y, acc[1][1]);
            acc[1][2] = fmaf(a.y, b.z, acc[1][2]); acc[1][3] = fmaf(a.y, b.w, acc[1][3]);
            acc[2][0] = fmaf(a.z, b.x, acc[2][0]); acc[2][1] = fmaf(a.z, b.y, acc[2][1]);
            acc[2][2] = fmaf(a.z, b.z, acc[2][2]); acc[2][3] = fmaf(a.z, b.w, acc[2][3]);
            acc[3][0] = fmaf(a.w, b.x, acc[3][0]); acc[3][1] = fmaf(a.w, b.y, acc[3][1]);
            acc[3][2] = fmaf(a.w, b.z, acc[3][2]); acc[3][3] = fmaf(a.w, b.w, acc[3][3]);
        }
        __syncthreads();
    }

    float* dst = pg + (size_t)ks * 262144;
    #pragma unroll
    for (int i = 0; i < 4; ++i)
        #pragma unroll
        for (int j = 0; j < 4; ++j)
            dst[(size_t)(tm0 + i) * 4096 + n0 + tn0 + j] = acc[i][j];
}

// ---------------------------------------------------------------------------
// Fused LSTM pointwise: sum 4 split-K partials + biases, update hx/cx,
// mirror hx into hx_all[t].
// ---------------------------------------------------------------------------
__global__ __launch_bounds__(256) void k_lstm_fuse(
    const float* __restrict__ pg, const float* __restrict__ b_ih,
    const float* __restrict__ b_hh, float* __restrict__ hx,
    float* __restrict__ cx, float* __restrict__ hx_all)
{
    int idx = blockIdx.x * 256 + threadIdx.x;
    int b = idx >> 10, u = idx & 1023;
    const float* g0 = pg + (size_t)b * 4096;
    float gi = 0.f, gf = 0.f, gg = 0.f, go = 0.f;
    #pragma unroll
    for (int ks = 0; ks < 4; ++ks) {
        const float* g = g0 + (size_t)ks * 262144;
        gi += g[u]; gf += g[1024 + u]; gg += g[2048 + u]; go += g[3072 + u];
    }
    gi += b_ih[u] + b_hh[u];
    gf += b_ih[1024 + u] + b_hh[1024 + u];
    gg += b_ih[2048 + u] + b_hh[2048 + u];
    go += b_ih[3072 + u] + b_hh[3072 + u];
    float c = sigmoidf_(gf) * cx[idx] + sigmoidf_(gi) * tanhf(gg);
    float h = sigmoidf_(go) * tanhf(c);
    cx[idx] = c; hx[idx] = h; hx_all[idx] = h;
}

// ---------------------------------------------------------------------------
__global__ __launch_bounds__(256) void k_fmean(const float* __restrict__ f,
                                               float* __restrict__ fmean)
{
    int b = blockIdx.x, tid = threadIdx.x;
    for (int e = tid; e < EMB; e += 256) {
        const float* fb = f + (size_t)b * HW * EMB + e;
        float s = 0.f;
        for (int h = 0; h < HW; ++h) s += fb[(size_t)h * EMB];
        fmean[b * EMB + e] = s * (1.0f / HW);
    }
}

__global__ __launch_bounds__(256) void k_init(
    const float* __restrict__ fmean,
    const float* __restrict__ W_hi, const float* __restrict__ b_hi,
    const float* __restrict__ W_ci, const float* __restrict__ b_ci,
    float* __restrict__ hx, float* __restrict__ cx)
{
    int b = blockIdx.x, tid = threadIdx.x;
    __shared__ float fm[EMB];
    for (int i = tid; i < EMB; i += 256) fm[i] = fmean[b * EMB + i];
    __syncthreads();
    for (int u = tid; u < HID; u += 256) {
        const float4* w1 = (const float4*)(W_hi + (size_t)u * EMB);
        const float4* w2 = (const float4*)(W_ci + (size_t)u * EMB);
        float a1 = b_hi[u], a2 = b_ci[u];
        for (int k = 0; k < EMB / 4; ++k) {
            float4 y1 = w1[k], y2 = w2[k];
            float x0 = fm[4*k], x1 = fm[4*k+1], x2 = fm[4*k+2], x3 = fm[4*k+3];
            a1 += x0*y1.x + x1*y1.y + x2*y1.z + x3*y1.w;
            a2 += x0*y2.x + x1*y2.y + x2*y2.z + x3*y2.w;
        }
        hx[b * HID + u] = a1;
        cx[b * HID + u] = a2;
    }
}

__global__ __launch_bounds__(128) void k_embed(const int* __restrict__ cap,
                                               const float* __restrict__ E,
                                               float* __restrict__ xs)
{
    int blk = blockIdx.x;
    int t = blk / BB, b = blk % BB;
    int c = cap[b * TT + t];
    const float4* src = (const float4*)(E + (size_t)c * EMB);
    float4* dst = (float4*)(xs + ((size_t)t * BB + b) * EMB);
    dst[threadIdx.x] = src[threadIdx.x];
}

// ---------------------------------------------------------------------------
// ha[b][a] = hx[b] . W2[a] + b2[a]   (grid = 64 blocks)
// ---------------------------------------------------------------------------
__global__ __launch_bounds__(256) void k_ha(
    const float* __restrict__ hx, const float* __restrict__ W2,
    const float* __restrict__ b2, float* __restrict__ ha)
{
    int b = blockIdx.x, tid = threadIdx.x;
    __shared__ __align__(16) float hx_s[HID];
    for (int i = tid; i < HID; i += 256) hx_s[i] = hx[b * HID + i];
    __syncthreads();
    for (int a = tid; a < ATT; a += 256) {
        const float4* w = (const float4*)(W2 + (size_t)a * HID);
        float acc = b2[a];
        #pragma unroll 4
        for (int k = 0; k < HID / 4; ++k) {
            float4 ww = w[k];
            float4 xx = *(const float4*)&hx_s[4 * k];
            acc += xx.x*ww.x + xx.y*ww.y + xx.z*ww.z + xx.w*ww.w;
        }
        ha[b * ATT + a] = acc;
    }
}

// ---------------------------------------------------------------------------
// logits[b][h] = sum_a tanh(fa[b][h][a]+ha[b][a])*V[a] + bV
// grid = 64*4: b = blk>>2, 49 h's per block.
// ---------------------------------------------------------------------------
__global__ __launch_bounds__(256) void k_logits(
    const float* __restrict__ fa, const float* __restrict__ ha,
    const float* __restrict__ V, const float* __restrict__ bV,
    float* __restrict__ logits)
{
    int blk = blockIdx.x;
    int b = blk >> 2, q = blk & 3;
    int tid = threadIdx.x;
    __shared__ float ha_s[ATT];
    __shared__ float V_s[ATT];
    for (int i = tid; i < ATT; i += 256) { ha_s[i] = ha[b * ATT + i]; V_s[i] = V[i]; }
    __syncthreads();

    int wid = tid >> 6, lane = tid & 63;
    float bv0 = bV[0];
    for (int h = q * 49 + wid; h < q * 49 + 49; h += 4) {
        const float* far = fa + ((size_t)b * HW + h) * ATT;
        float p = 0.f;
        #pragma unroll
        for (int i = 0; i < ATT / 64; ++i) {
            int a = lane + (i << 6);
            p += tanhf(far[a] + ha_s[a]) * V_s[a];
        }
        #pragma unroll
        for (int off = 32; off > 0; off >>= 1) p += __shfl_down(p, off);
        if (lane == 0) logits[b * HW + h] = p + bv0;
    }
}

// ---------------------------------------------------------------------------
// ctx[b][e] = softmax_h(logits[b]) . f[b][:][e]   (grid = 64*4)
// ---------------------------------------------------------------------------
__global__ __launch_bounds__(256) void k_ctx(
    const float* __restrict__ logits, const float* __restrict__ f,
    float* __restrict__ ctx)
{
    int blk = blockIdx.x;
    int b = blk >> 2, eg = blk & 3;
    int tid = threadIdx.x;
    __shared__ float w_s[HW];
    __shared__ float red_s[256];
    __shared__ float part[128];

    float v = (tid < HW) ? logits[b * HW + tid] : -INFINITY;
    red_s[tid] = v; __syncthreads();
    for (int s = 128; s > 0; s >>= 1) {
        if (tid < s) red_s[tid] = fmaxf(red_s[tid], red_s[tid + s]);
        __syncthreads();
    }
    float mx = red_s[0]; __syncthreads();
    float e = (tid < HW) ? expf(v - mx) : 0.f;
    red_s[tid] = e; __syncthreads();
    for (int s = 128; s > 0; s >>= 1) {
        if (tid < s) red_s[tid] += red_s[tid + s];
        __syncthreads();
    }
    float inv = 1.0f / red_s[0];
    if (tid < HW) w_s[tid] = e * inv;
    __syncthreads();

    int e0 = (eg << 7) + (tid & 127);
    int half = tid >> 7;
    const float* fb = f + (size_t)b * HW * EMB + e0;
    float s = 0.f;
    int h0 = half * 98;
    for (int h = h0; h < h0 + 98; ++h)
        s = fmaf(w_s[h], fb[(size_t)h * EMB], s);
    if (half) part[tid & 127] = s;
    __syncthreads();
    if (!half) ctx[b * EMB + e0] = s + part[tid];
}

// ---------------------------------------------------------------------------
extern "C" void kernel_launch(void* const* d_in, const int* in_sizes, int n_in,
                              void* d_out, int out_size, void* d_ws, size_t ws_size,
                              hipStream_t stream) {
    const float* features = (const float*)d_in[0];
    const int*   captions = (const int*)d_in[1];
    const float* E      = (const float*)d_in[3];
    const float* W_feat = (const float*)d_in[4];
    const float* b_feat = (const float*)d_in[5];
    const float* W1     = (const float*)d_in[6];
    const float* b1     = (const float*)d_in[7];
    const float* W2     = (const float*)d_in[8];
    const float* b2     = (const float*)d_in[9];
    const float* V      = (const float*)d_in[10];
    const float* bV     = (const float*)d_in[11];
    const float* W_hi   = (const float*)d_in[12];
    const float* b_hi   = (const float*)d_in[13];
    const float* W_ci   = (const float*)d_in[14];
    const float* b_ci   = (const float*)d_in[15];
    const float* W_ih   = (const float*)d_in[16];
    const float* b_ih   = (const float*)d_in[17];
    const float* W_hh   = (const float*)d_in[18];
    const float* b_hh   = (const float*)d_in[19];
    const float* W_out  = (const float*)d_in[20];
    const float* b_out  = (const float*)d_in[21];
    float* out = (float*)d_out;

    // ---- workspace layout (floats first, then ushort planes) ----
    float* ws = (float*)d_ws;
    float* f_buf  = ws;                          // 6,422,528
    float* fa_buf = f_buf + 6422528;             // 6,422,528
    float* xs     = fa_buf + 6422528;            // 622,592
    float* fmean  = xs + 622592;                 // 32,768
    float* hx     = fmean + 32768;               // 65,536
    float* cx     = hx + 65536;                  // 65,536
    float* ctx    = cx + 65536;                  // 32,768
    float* logits = ctx + 32768;                 // 12,544
    float* ha     = logits + 12544;              // 32,768
    float* pg     = ha + 32768;                  // 4*262,144 = 1,048,576
    float* hx_all = pg + 1048576;                // 1280*1024 = 1,310,720
    ushort* wfeat_hi = (ushort*)(hx_all + 1310720);     // 1,048,576 each
    ushort* wfeat_lo = wfeat_hi + 1048576;
    ushort* w1_hi    = wfeat_lo + 1048576;              // 262,144 each
    ushort* w1_lo    = w1_hi + 262144;
    // W_out planes reuse f_buf/fa_buf region after the step loop (41MB <= 51MB)
    ushort* wout_hi = (ushort*)f_buf;                   // 10,240,000 each
    ushort* wout_lo = wout_hi + 10240000;

    // ---- precompute ----
    k_split<<<1048576 / 4 / 256, 256, 0, stream>>>(W_feat, wfeat_hi, wfeat_lo, 1048576);
    k_split<<<262144 / 4 / 256, 256, 0, stream>>>(W1, w1_hi, w1_lo, 262144);
    // f = features @ W_feat^T + b_feat  [12544,512], K=2048
    mfma_nt<<<dim3(2, 196), 256, 0, stream>>>(
        features, wfeat_hi, wfeat_lo, b_feat, f_buf, 12544, 512, 2048, 512);
    // fa = f @ W1^T + b1  [12544,512], K=512
    mfma_nt<<<dim3(2, 196), 256, 0, stream>>>(
        f_buf, w1_hi, w1_lo, b1, fa_buf, 12544, 512, 512, 512);
    k_fmean<<<BB, 256, 0, stream>>>(f_buf, fmean);
    k_init<<<BB, 256, 0, stream>>>(fmean, W_hi, b_hi, W_ci, b_ci, hx, cx);
    k_embed<<<STEPS * BB, 128, 0, stream>>>(captions, E, xs);

    // ---- recurrent steps ----
    for (int t = 0; t < STEPS; ++t) {
        k_ha<<<BB, 256, 0, stream>>>(hx, W2, b2, ha);
        k_logits<<<BB * 4, 256, 0, stream>>>(fa_buf, ha, V, bV, logits);
        k_ctx<<<BB * 4, 256, 0, stream>>>(logits, f_buf, ctx);
        gemm_gates_ks<<<dim3(64, 4), 256, 0, stream>>>(
            xs + (size_t)t * BB * EMB, ctx, hx, W_ih, W_hh, pg);
        k_lstm_fuse<<<256, 256, 0, stream>>>(
            pg, b_ih, b_hh, hx, cx, hx_all + (size_t)t * BB * HID);
    }

    // ---- vocab projection over all steps at once: [1216,10000], K=1024 ----
    k_split<<<10240000 / 4 / 256, 256, 0, stream>>>(W_out, wout_hi, wout_lo, 10240000);
    mfma_nt<<<dim3(40, 20), 256, 0, stream>>>(
        hx_all, wout_hi, wout_lo, b_out, out, STEPS * BB, VOCAB, HID, VOCAB);
}